// Round 8
// baseline (323.970 us; speedup 1.0000x reference)
//
#include <hip/hip_runtime.h>

typedef short bf16x8 __attribute__((ext_vector_type(8)));
typedef float f32x4 __attribute__((ext_vector_type(4)));

__device__ __forceinline__ float b2f(unsigned short u) {
  union { unsigned int i; float f; } v; v.i = ((unsigned int)u) << 16; return v.f;
}
__device__ __forceinline__ unsigned short f2b(float f) {
  unsigned int u = __float_as_uint(f);
  u += 0x7fffu + ((u >> 16) & 1u);
  return (unsigned short)(u >> 16);
}
__device__ __forceinline__ float silu_f(float s) { return s / (1.0f + __expf(-s)); }

// split fp32 -> (hi, lo) bf16
__device__ __forceinline__ void split2(float f, unsigned short& h, unsigned short& l) {
  h = f2b(f);
  l = f2b(f - b2f(h));
}

// async 16B/lane global->LDS. LDS dest = wave-uniform base + lane*16 (linear).
__device__ __forceinline__ void gload16(const unsigned short* g, unsigned short* l) {
  __builtin_amdgcn_global_load_lds(
      (const __attribute__((address_space(1))) unsigned int*)g,
      (__attribute__((address_space(3))) unsigned int*)l, 16, 0, 0);
}

// unpack 8 packed (hi | lo<<16) u32 -> hi/lo bf16x8 via v_perm (2 ops per pair)
__device__ __forceinline__ void unpack8(const unsigned* p, bf16x8& hi, bf16x8& lo) {
  uint4 a = *(const uint4*)p;
  uint4 b = *(const uint4*)(p + 4);
  unsigned u[8] = {a.x, a.y, a.z, a.w, b.x, b.y, b.z, b.w};
  unsigned hw[4], lw[4];
  #pragma unroll
  for (int j = 0; j < 4; j++) {
    hw[j] = __builtin_amdgcn_perm(u[2 * j + 1], u[2 * j], 0x05040100u);
    lw[j] = __builtin_amdgcn_perm(u[2 * j + 1], u[2 * j], 0x07060302u);
  }
  hi = *(bf16x8*)hw;
  lo = *(bf16x8*)lw;
}

// K1 (fused): blocks 0..95: W fp32 -> fragment-major split-bf16 planes
//   Wfq/Wfl (q,k rows; hi/lo) and Wfv (v rows; hi): [(h*8+step)*nf + frag][lane]*8
//   so k_qkl's A-frag loads are 1KB-coalesced and L2-hot.
// blocks 96..: prep: x_preact = silu(x+pab) fp32 -> out[:,0:256];
//   T = x_preact + pqb TRANSPOSED split planes -> out[:,256:512]
//   (u32-granular XOR-swizzled LDS transpose: bank-conflict-free)
__global__ __launch_bounds__(256) void k_prep(
    const float* __restrict__ x, const float* __restrict__ pab,
    const float* __restrict__ pqb, const float* __restrict__ W,
    unsigned short* __restrict__ Wfq, unsigned short* __restrict__ Wfl,
    unsigned short* __restrict__ Wfv, float* __restrict__ out) {
  __shared__ unsigned th2[64 * 32], tl2[64 * 32];  // u32 [n][cpair], XOR-swizzled
  int blk = blockIdx.x;
  if (blk < 96) {  // ---- W fragment split (one thread = one 16B frag-slice) ----
    int u = blk * 256 + threadIdx.x;  // 0..24575
    int lane = u & 63, l15 = lane & 15, l4 = lane >> 4;
    int row, k;
    unsigned short* dh;
    unsigned short* dl = nullptr;
    if (u < 16384) {  // q/k frags: i 0-1 = q, 2-3 = k
      int i = (u >> 6) & 3, step = (u >> 8) & 7, hh = u >> 11;
      row = (i < 2) ? (hh * 32 + i * 16 + l15) : (256 + hh * 32 + (i - 2) * 16 + l15);
      k = step * 32 + l4 * 8;
      dh = Wfq + (long long)u * 8;
      dl = Wfl + (long long)u * 8;
    } else {  // v frags (hi only)
      int u2 = u - 16384;
      int i2 = (u2 >> 6) & 1, step = (u2 >> 7) & 7, hh = u2 >> 10;
      row = 512 + hh * 32 + i2 * 16 + l15;
      k = step * 32 + l4 * 8;
      dh = Wfv + (long long)u2 * 8;
    }
    float4 a = *(const float4*)(W + row * 256 + k);
    float4 bq = *(const float4*)(W + row * 256 + k + 4);
    float v[8] = {a.x, a.y, a.z, a.w, bq.x, bq.y, bq.z, bq.w};
    unsigned short h8[8], l8[8];
    #pragma unroll
    for (int j = 0; j < 8; j++) split2(v[j], h8[j], l8[j]);
    uint4 ph;
    ph.x = h8[0] | ((unsigned)h8[1] << 16); ph.y = h8[2] | ((unsigned)h8[3] << 16);
    ph.z = h8[4] | ((unsigned)h8[5] << 16); ph.w = h8[6] | ((unsigned)h8[7] << 16);
    *(uint4*)dh = ph;
    if (dl) {
      uint4 pl;
      pl.x = l8[0] | ((unsigned)l8[1] << 16); pl.y = l8[2] | ((unsigned)l8[3] << 16);
      pl.z = l8[4] | ((unsigned)l8[5] << 16); pl.w = l8[6] | ((unsigned)l8[7] << 16);
      *(uint4*)dl = pl;
    }
    return;
  }
  blk -= 96;  // ---- prep ----
  int nb = blk & 63;
  int cb = (blk >> 6) & 3;
  int b = blk >> 8;
  int n0 = nb * 64, c0 = cb * 64;
  int t = threadIdx.x;
  int nn = (t & 15) * 4;
  #pragma unroll
  for (int p = 0; p < 2; p++) {
    int cp = p * 16 + (t >> 4);  // channel pair index within 64-c tile
    int c = 2 * cp;
    float pa0 = pab[c0 + c], pq0 = pqb[c0 + c];
    float pa1 = pab[c0 + c + 1], pq1 = pqb[c0 + c + 1];
    float4 x0 = *(const float4*)(x + ((long long)(b * 256 + c0 + c)) * 4096 + n0 + nn);
    float4 x1 = *(const float4*)(x + ((long long)(b * 256 + c0 + c + 1)) * 4096 + n0 + nn);
    float s0[4] = {silu_f(x0.x + pa0), silu_f(x0.y + pa0),
                   silu_f(x0.z + pa0), silu_f(x0.w + pa0)};
    float s1[4] = {silu_f(x1.x + pa1), silu_f(x1.y + pa1),
                   silu_f(x1.z + pa1), silu_f(x1.w + pa1)};
    float4 sv0 = {s0[0], s0[1], s0[2], s0[3]};
    float4 sv1 = {s1[0], s1[1], s1[2], s1[3]};
    *(float4*)(out + ((long long)(b * 512 + c0 + c)) * 4096 + n0 + nn) = sv0;
    *(float4*)(out + ((long long)(b * 512 + c0 + c + 1)) * 4096 + n0 + nn) = sv1;
    float t0[4] = {s0[0] + pq0, s0[1] + pq0, s0[2] + pq0, s0[3] + pq0};
    float t1[4] = {s1[0] + pq1, s1[1] + pq1, s1[2] + pq1, s1[3] + pq1};
    #pragma unroll
    for (int j = 0; j < 4; j++) {
      int nr = nn + j;
      unsigned short h0, l0, h1, l1;
      split2(t0[j], h0, l0);
      split2(t1[j], h1, l1);
      int pidx = nr * 32 + (cp ^ (nr & 31));  // u32 XOR swizzle: ~2-way banks
      th2[pidx] = (unsigned)h0 | ((unsigned)h1 << 16);
      tl2[pidx] = (unsigned)l0 | ((unsigned)l1 << 16);
    }
  }
  __syncthreads();
  unsigned short* Th = (unsigned short*)(out + ((long long)(b * 512 + 256)) * 4096);
  unsigned short* Tl = Th + 4096 * 256;
  #pragma unroll
  for (int q = 0; q < 2; q++) {
    int s = q * 256 + t;
    int n = s >> 3, sc = s & 7;
    unsigned wh[4], wl[4];
    #pragma unroll
    for (int j = 0; j < 4; j++) {
      int pidx = n * 32 + ((sc * 4 + j) ^ (n & 31));
      wh[j] = th2[pidx];
      wl[j] = tl2[pidx];
    }
    uint4 vh = {wh[0], wh[1], wh[2], wh[3]};
    uint4 vl = {wl[0], wl[1], wl[2], wl[3]};
    *(uint4*)(Th + (long long)(n0 + n) * 256 + c0 + sc * 8) = vh;
    *(uint4*)(Tl + (long long)(n0 + n) * 256 + c0 + sc * 8) = vl;
  }
}

// K2: fused q/k/v GEMM + logits. One block = (b, head, ntile of 128 n).
// A-frags (q/k hi+lo, v hi) loaded DIRECTLY global->VGPR from the frag-major
// L2-hot planes (1KB coalesced per load, issued before the barrier so the
// existing vmcnt drain covers their latency). LDS stages only B (T planes,
// 16KB, gload_lds + XOR swizzle). LDS-pipe ops per wave per step: 8 (was ~20).
// Epilogue: v -> kv fp32; q/k +bias+PE(+FiLM) packed -> qk LDS tile
// (stride 132 u32: logits-phase reads ~2-way banks instead of 16-way).
// Logits: q.k^T, cross-wave reduce (stride-33 rows), atomicAdd into logits.
__global__ __launch_bounds__(256, 3) void k_qkl(
    const unsigned short* __restrict__ Wfq, const unsigned short* __restrict__ Wfl,
    const unsigned short* __restrict__ Wfv,
    const float* __restrict__ qkvb,
    const float* __restrict__ peqh, const float* __restrict__ peqw,
    const float* __restrict__ pekh, const float* __restrict__ pekw,
    const float* __restrict__ modm, const float* __restrict__ modb,
    const float* __restrict__ outT, float* __restrict__ kv,
    float* __restrict__ logits) {
  __shared__ __align__(16) unsigned char smem[33792];
  unsigned short* stg = (unsigned short*)smem;  // B staging: 16KB
  unsigned* qk = (unsigned*)smem;               // 64 x 132 u32 = 33792B
  float* red = (float*)smem;                    // 4 x 1056 f32 = 16896B

  int bx = blockIdx.x;
  int ntile = bx & 31, h = (bx >> 5) & 7, b = bx >> 8;
  int n0 = ntile * 128;
  int t = threadIdx.x, lane = t & 63, w = t >> 6;
  int l15 = lane & 15, l4 = lane >> 4;

  const unsigned short* Th =
      (const unsigned short*)(outT + ((long long)(b * 512 + 256)) * 4096);
  const unsigned short* Tl = Th + 4096 * 256;

  // B staging: 16 x 1KB chunks (Bh 0-7, Bl 8-15); wave w stages w, w+4, w+8, w+12
  const unsigned short* csrc[4];
  unsigned short* cdst[4];
  int lrow = lane >> 2;
  int lslot = ((lane & 3) ^ ((lane >> 3) & 3)) * 8;  // source-side swizzle
  #pragma unroll
  for (int i = 0; i < 4; i++) {
    int c = w + 4 * i;
    const unsigned short* plane = (c < 8) ? Th : Tl;
    int rowb = n0 + (c & 7) * 16;
    csrc[i] = plane + (long long)(rowb + lrow) * 256 + lslot;
    cdst[i] = stg + c * 512;
  }

  // A fragment per-lane bases (frag-major layout)
  const unsigned short* aqb = Wfq + (long long)(h * 32) * 512 + lane * 8;
  const unsigned short* alb = Wfl + (long long)(h * 32) * 512 + lane * 8;
  const unsigned short* avb = Wfv + (long long)(h * 16) * 512 + lane * 8;

  int sw = (l4 ^ ((l15 >> 1) & 3)) << 3;  // read-side swizzle
  f32x4 z = {0.f, 0.f, 0.f, 0.f};
  f32x4 acc[4][2];   // q/k rows 0..63
  f32x4 accv[2][2];  // v rows 0..31
  #pragma unroll
  for (int i = 0; i < 4; i++)
    #pragma unroll
    for (int j = 0; j < 2; j++) acc[i][j] = z;
  #pragma unroll
  for (int i = 0; i < 2; i++)
    #pragma unroll
    for (int j = 0; j < 2; j++) accv[i][j] = z;

  for (int step = 0; step < 8; ++step) {
    int k0 = step * 32;
    #pragma unroll
    for (int i = 0; i < 4; i++) gload16(csrc[i] + k0, cdst[i]);
    // A loads (global->VGPR, L2-hot): latency covered by the barrier drain
    bf16x8 ah[4], alo[4], av[2];
    #pragma unroll
    for (int i = 0; i < 4; i++) {
      ah[i]  = *(const bf16x8*)(aqb + (step * 4 + i) * 512);
      alo[i] = *(const bf16x8*)(alb + (step * 4 + i) * 512);
    }
    #pragma unroll
    for (int i = 0; i < 2; i++)
      av[i] = *(const bf16x8*)(avb + (step * 2 + i) * 512);
    __syncthreads();  // drains gload_lds + A loads
    bf16x8 bh[2], bl[2];
    #pragma unroll
    for (int j = 0; j < 2; j++) {
      int ro = (w * 32 + j * 16 + l15) * 32 + sw;
      bh[j] = *(const bf16x8*)(stg + ro);
      bl[j] = *(const bf16x8*)(stg + 4096 + ro);
    }
    // v (single-term; av dies early)
    #pragma unroll
    for (int i = 0; i < 2; i++)
      #pragma unroll
      for (int j = 0; j < 2; j++)
        accv[i][j] = __builtin_amdgcn_mfma_f32_16x16x32_bf16(av[i], bh[j], accv[i][j], 0, 0, 0);
    // qk (3-term split-bf16)
    #pragma unroll
    for (int i = 0; i < 4; i++)
      #pragma unroll
      for (int j = 0; j < 2; j++) {
        acc[i][j] = __builtin_amdgcn_mfma_f32_16x16x32_bf16(ah[i], bh[j], acc[i][j], 0, 0, 0);
        acc[i][j] = __builtin_amdgcn_mfma_f32_16x16x32_bf16(ah[i], bl[j], acc[i][j], 0, 0, 0);
        acc[i][j] = __builtin_amdgcn_mfma_f32_16x16x32_bf16(alo[i], bh[j], acc[i][j], 0, 0, 0);
      }
    __syncthreads();  // protect stg from next step's gload overwrite
  }

  // v epilogue: bias only -> kv fp32 (frees accv)
  int b256 = b * 256;
  #pragma unroll
  for (int i = 0; i < 2; i++) {
    #pragma unroll
    for (int r = 0; r < 4; r++) {
      int row = i * 16 + l4 * 4 + r;  // 0..31
      int cch = h * 32 + row;
      float bias = qkvb[512 + cch];
      #pragma unroll
      for (int j = 0; j < 2; j++) {
        int n = n0 + w * 32 + j * 16 + l15;
        kv[((long long)(b256 + cch)) * 4096 + n] = accv[i][j][r] + bias;
      }
    }
  }

  // q/k epilogue: bias + PE (+FiLM for q), pack, store to qk tile (stride 132)
  #pragma unroll
  for (int i = 0; i < 4; i++) {
    #pragma unroll
    for (int r = 0; r < 4; r++) {
      int row = i * 16 + l4 * 4 + r;  // 0..63; i<2 -> q, i>=2 -> k
      int cch = h * 32 + (row & 31);
      float bias = qkvb[(row & 32) ? (256 + cch) : cch];
      float mm = 0.f, mb = 0.f;
      if (row < 32) { mm = modm[b256 + cch]; mb = modb[b256 + cch]; }
      #pragma unroll
      for (int j = 0; j < 2; j++) {
        int nl = w * 32 + j * 16 + l15;
        int n = n0 + nl;
        int hh = n >> 6, ww = n & 63;
        float v = acc[i][j][r] + bias;
        if (row < 32) {
          v += peqh[cch * 64 + hh] + peqw[cch * 64 + ww];
          v = v * mm + mb;
        } else {
          v += pekh[cch * 64 + hh] + pekw[cch * 64 + ww];
        }
        unsigned short hi_, lo_;
        split2(v, hi_, lo_);
        int pch = (nl >> 3) ^ (row & 15);  // chunk swizzle (8 u32 = 32B chunks)
        qk[row * 132 + pch * 8 + (nl & 7)] = (unsigned)hi_ | ((unsigned)lo_ << 16);
      }
    }
  }
  __syncthreads();

  // logits partial: q(32 x 128n) . k(32 x 128n)^T; wave w covers n-slice w*32..
  f32x4 acc2[2][2] = {z, z, z, z};
  int chn = w * 4 + l4;
  bf16x8 qh[2], ql[2], kh[2], kl[2];
  #pragma unroll
  for (int i2 = 0; i2 < 2; i2++) {
    int row = i2 * 16 + l15;
    unpack8(qk + row * 132 + ((chn ^ l15) << 3), qh[i2], ql[i2]);
    unpack8(qk + (row + 32) * 132 + ((chn ^ l15) << 3), kh[i2], kl[i2]);
  }
  acc2[0][0] = __builtin_amdgcn_mfma_f32_16x16x32_bf16(qh[0], kh[0], acc2[0][0], 0, 0, 0);
  acc2[0][0] = __builtin_amdgcn_mfma_f32_16x16x32_bf16(qh[0], kl[0], acc2[0][0], 0, 0, 0);
  acc2[0][0] = __builtin_amdgcn_mfma_f32_16x16x32_bf16(ql[0], kh[0], acc2[0][0], 0, 0, 0);
  acc2[0][1] = __builtin_amdgcn_mfma_f32_16x16x32_bf16(qh[0], kh[1], acc2[0][1], 0, 0, 0);
  acc2[0][1] = __builtin_amdgcn_mfma_f32_16x16x32_bf16(qh[0], kl[1], acc2[0][1], 0, 0, 0);
  acc2[0][1] = __builtin_amdgcn_mfma_f32_16x16x32_bf16(ql[0], kh[1], acc2[0][1], 0, 0, 0);
  acc2[1][0] = __builtin_amdgcn_mfma_f32_16x16x32_bf16(qh[1], kh[0], acc2[1][0], 0, 0, 0);
  acc2[1][0] = __builtin_amdgcn_mfma_f32_16x16x32_bf16(qh[1], kl[0], acc2[1][0], 0, 0, 0);
  acc2[1][0] = __builtin_amdgcn_mfma_f32_16x16x32_bf16(ql[1], kh[0], acc2[1][0], 0, 0, 0);
  acc2[1][1] = __builtin_amdgcn_mfma_f32_16x16x32_bf16(qh[1], kh[1], acc2[1][1], 0, 0, 0);
  acc2[1][1] = __builtin_amdgcn_mfma_f32_16x16x32_bf16(qh[1], kl[1], acc2[1][1], 0, 0, 0);
  acc2[1][1] = __builtin_amdgcn_mfma_f32_16x16x32_bf16(ql[1], kh[1], acc2[1][1], 0, 0, 0);

  // red aliases qk: wait for ALL waves' qk reads before overwriting
  __syncthreads();
  #pragma unroll
  for (int i2 = 0; i2 < 2; i2++)
    #pragma unroll
    for (int j2 = 0; j2 < 2; j2++)
      #pragma unroll
      for (int r = 0; r < 4; r++)
        red[w * 1056 + (i2 * 16 + l4 * 4 + r) * 33 + j2 * 16 + l15] = acc2[i2][j2][r];
  __syncthreads();
  const float scale = 0.1767766952966369f;  // 1/sqrt(32)
  int bhid = b * 8 + h;
  #pragma unroll
  for (int i = 0; i < 4; i++) {
    int idx = i * 256 + t;
    int crow = idx >> 5, dcol = idx & 31;
    int ro = crow * 33 + dcol;
    float s = (red[ro] + red[1056 + ro] + red[2112 + ro] + red[3168 + ro]) * scale;
    atomicAdd(logits + (long long)bhid * 1024 + idx, s);
  }
}

// K3: softmax (logits already summed by atomics, already scaled) + weights @ v
__global__ __launch_bounds__(256) void k_pv(
    const float* __restrict__ kv,    // v
    const float* __restrict__ logits,
    float* __restrict__ out) {
  int bx = blockIdx.x;
  int ntile = bx & 15, bh = bx >> 4;
  int b = bh >> 3, h = bh & 7;
  int t = threadIdx.x;
  __shared__ float raw[32][33];   // [c][d], padded: serial reads conflict-free
  __shared__ float wsm[32][33];
  #pragma unroll
  for (int i = 0; i < 4; i++) {
    int idx = i * 256 + t;
    raw[idx >> 5][idx & 31] = logits[(long long)bh * 1024 + idx];
  }
  __syncthreads();
  if (t < 32) {
    float mx = -1e30f;
    for (int d = 0; d < 32; d++) mx = fmaxf(mx, raw[t][d]);
    float e[32]; float s = 0.f;
    for (int d = 0; d < 32; d++) { e[d] = __expf(raw[t][d] - mx); s += e[d]; }
    float inv = 1.0f / s;
    for (int d = 0; d < 32; d++) wsm[t][d] = e[d] * inv;
  }
  __syncthreads();
  int rg = t >> 6;          // wave-uniform -> wsm broadcast
  int nl = (t & 63) * 4;
  int n0 = ntile * 256 + nl;
  const float* vb = kv + ((long long)(b * 256 + h * 32)) * 4096 + n0;
  float acc[8][4];
  #pragma unroll
  for (int r = 0; r < 8; r++)
    #pragma unroll
    for (int i = 0; i < 4; i++) acc[r][i] = 0.f;
  for (int d = 0; d < 32; d++) {
    float4 vv = *(const float4*)(vb + (long long)d * 4096);
    #pragma unroll
    for (int r = 0; r < 8; r++) {
      float wv = wsm[rg * 8 + r][d];
      acc[r][0] += wv * vv.x; acc[r][1] += wv * vv.y;
      acc[r][2] += wv * vv.z; acc[r][3] += wv * vv.w;
    }
  }
  #pragma unroll
  for (int r = 0; r < 8; r++) {
    long long oidx = ((long long)(b * 512 + 256 + h * 32 + rg * 8 + r)) * 4096 + n0;
    float4 ov = {acc[r][0], acc[r][1], acc[r][2], acc[r][3]};
    *(float4*)(out + oidx) = ov;
  }
}

extern "C" void kernel_launch(void* const* d_in, const int* in_sizes, int n_in,
                              void* d_out, int out_size, void* d_ws, size_t ws_size,
                              hipStream_t stream) {
  const float* x    = (const float*)d_in[0];
  const float* modm = (const float*)d_in[1];
  const float* modb = (const float*)d_in[2];
  const float* Wq   = (const float*)d_in[3];
  const float* qkvb = (const float*)d_in[4];
  const float* peqh = (const float*)d_in[5];
  const float* peqw = (const float*)d_in[6];
  const float* pekh = (const float*)d_in[7];
  const float* pekw = (const float*)d_in[8];
  const float* pab  = (const float*)d_in[9];
  const float* pqb  = (const float*)d_in[10];
  float* out = (float*)d_out;

  // ws layout (67 MB total, <= 69.2 MB proven):
  //   [0, 640KB)     Wfq(256KB) | Wfl(256KB) | Wfv(128KB) frag-major planes
  //   [1MB, 1.5MB)   logits f32[16][8][32][32] (atomic-accumulated, pre-scaled)
  //   [3MB, 67MB)    v fp32 [16][256][4096]
  unsigned short* Wfq = (unsigned short*)d_ws;
  unsigned short* Wfl = Wfq + 131072;
  unsigned short* Wfv = Wfl + 131072;
  float* logits = (float*)((char*)d_ws + (1 << 20));
  float* kv = (float*)((char*)d_ws + 3 * (1 << 20));

  hipMemsetAsync(logits, 0, 16 * 8 * 32 * 32 * sizeof(float), stream);
  k_prep<<<4192, 256, 0, stream>>>(x, pab, pqb, Wq, Wfq, Wfl, Wfv, out);
  k_qkl<<<4096, 256, 0, stream>>>(Wfq, Wfl, Wfv, qkvb, peqh, peqw, pekh, pekw,
                                  modm, modb, out, kv, logits);
  k_pv<<<2048, 256, 0, stream>>>(kv, logits, out);
}